// Round 3
// baseline (2571.544 us; speedup 1.0000x reference)
//
#include <hip/hip_runtime.h>
#include <cfloat>
#include <cstdint>

#define F_FEAT 256
#define NHID 128
#define NCLASS 16
#define KTOP 5

#define BR 128
#define BC 128
#define NSPLIT 16
#define QCAP 448

typedef __attribute__((ext_vector_type(8))) short bf16x8;
typedef __attribute__((ext_vector_type(4))) float f32x4;

// ---------------- helpers ----------------
__device__ __forceinline__ void topk_insert5(float (&v)[5], int (&ix)[5], float cv, int ci) {
  // rank order: (value desc, index asc)  -- matches jax.lax.top_k
  if (cv < v[4] || (cv == v[4] && ci > ix[4])) return;
  int pos = 0;
#pragma unroll
  for (int j = 0; j < 5; ++j) pos += ((v[j] > cv) || (v[j] == cv && ix[j] < ci)) ? 1 : 0;
  if (pos >= 5) return;
  for (int j = 4; j > pos; --j) { v[j] = v[j - 1]; ix[j] = ix[j - 1]; }
  v[pos] = cv; ix[pos] = ci;
}

__device__ __forceinline__ unsigned short f2bf(float f) {
  unsigned u = __float_as_uint(f);
  unsigned r = (u + 0x7fffu + ((u >> 16) & 1u)) >> 16;
  return (unsigned short)r;
}
__device__ __forceinline__ float bf2f(unsigned short h) {
  return __uint_as_float(((unsigned)h) << 16);
}

// ---------------- graph prep ----------------
__global__ void k_deg_count(const int* __restrict__ ar, const float* __restrict__ av,
                            const int* __restrict__ nr, const float* __restrict__ nv,
                            float* deg_adj, float* deg_ned, int* cntA, int* cntN, int E) {
  int e = blockIdx.x * blockDim.x + threadIdx.x;
  if (e >= E) return;
  int ra = ar[e]; int rn = nr[e];
  atomicAdd(&deg_adj[ra], av[e]);
  atomicAdd(&deg_ned[rn], nv[e]);
  atomicAdd(&cntA[ra], 1);
  atomicAdd(&cntN[rn], 1);
}

__global__ __launch_bounds__(1024) void k_scan_pair(const int* c0, int* o0, const int* c1, int* o1, int n) {
  const int* c = (blockIdx.x == 0) ? c0 : c1;
  int* o = (blockIdx.x == 0) ? o0 : o1;
  if (c == nullptr) return;
  __shared__ int buf[1024];
  int tid = threadIdx.x;
  int base = 0;
  int chunks = (n + 1023) >> 10;
  for (int ch = 0; ch < chunks; ++ch) {
    int i = (ch << 10) + tid;
    buf[tid] = (i < n) ? c[i] : 0;
    __syncthreads();
    for (int offd = 1; offd < 1024; offd <<= 1) {
      int t = (tid >= offd) ? buf[tid - offd] : 0;
      __syncthreads();
      buf[tid] += t;
      __syncthreads();
    }
    if (i < n) o[i + 1] = base + buf[tid];
    int tot = buf[1023];
    __syncthreads();
    base += tot;
  }
  if (tid == 0) o[0] = 0;
}

__global__ void k_rs(const float* deg_adj, const float* deg_ned, float* rs_adj, float* rinv_ned, int N) {
  int i = blockIdx.x * blockDim.x + threadIdx.x;
  if (i >= N) return;
  rs_adj[i] = 1.0f / (sqrtf(deg_adj[i]) + 1e-10f);
  rinv_ned[i] = 1.0f / (deg_ned[i] + 1e-10f);
}

__global__ void k_fill2(const int* ar, const int* nr, const int* rpA, const int* rpN,
                        int* fillA, int* fillN, int* permA, int* permN, int E) {
  int e = blockIdx.x * blockDim.x + threadIdx.x;
  if (e >= E) return;
  int ra = ar[e];
  permA[rpA[ra] + atomicAdd(&fillA[ra], 1)] = e;
  int rn = nr[e];
  permN[rpN[rn] + atomicAdd(&fillN[rn], 1)] = e;
}

__global__ void k_edgeval(const int* ar, const int* ac, const float* av,
                          const int* nr, const float* nv,
                          const float* rs_adj, const float* rinv_ned,
                          float* adj_sym, float* ned_rw, int E) {
  int e = blockIdx.x * blockDim.x + threadIdx.x;
  if (e >= E) return;
  adj_sym[e] = av[e] * rs_adj[ar[e]] * rs_adj[ac[e]];
  ned_rw[e] = nv[e] * rinv_ned[nr[e]];
}

// ---------------- SpMMs (CSR, block per row, feature per thread) ----------------
__global__ void k_spmm1(const int* __restrict__ rpA, const int* __restrict__ permA,
                        const int* __restrict__ ac, const float* __restrict__ adj_sym,
                        const float* __restrict__ x, const float* __restrict__ Wd1,
                        float* __restrict__ emb, int N) {
  int r = blockIdx.x; int f = threadIdx.x;
  int s = rpA[r], e = rpA[r + 1];
  float acc = 0.f;
  for (int i = s; i < e; ++i) {
    int id = permA[i];
    acc += adj_sym[id] * x[(size_t)ac[id] * F_FEAT + f];
  }
  emb[(size_t)r * F_FEAT + f] = tanhf(acc * Wd1[f]);
}

__global__ void k_spmm2_norm(const int* __restrict__ rpA, const int* __restrict__ permA,
                             const int* __restrict__ ac, const float* __restrict__ adj_sym,
                             const float* __restrict__ emb, const float* __restrict__ Wd2,
                             float* __restrict__ embn, int N) {
  __shared__ float red[F_FEAT];
  int r = blockIdx.x; int f = threadIdx.x;
  int s = rpA[r], e = rpA[r + 1];
  float acc = 0.f;
  for (int i = s; i < e; ++i) {
    int id = permA[i];
    acc += adj_sym[id] * emb[(size_t)ac[id] * F_FEAT + f];
  }
  float val = acc * Wd2[f];
  red[f] = val * val;
  __syncthreads();
  for (int st = F_FEAT / 2; st > 0; st >>= 1) {
    if (f < st) red[f] += red[f + st];
    __syncthreads();
  }
  float rinv = 1.0f / (sqrtf(red[0]) + 1e-12f);
  embn[(size_t)r * F_FEAT + f] = val * rinv;
}

__global__ void k_spmmT(const int* __restrict__ rpN, const int* __restrict__ permN,
                        const int* __restrict__ nc, const float* __restrict__ ned_rw,
                        const float* __restrict__ embn, float* __restrict__ Tm, int N) {
  int r = blockIdx.x; int f = threadIdx.x;
  int s = rpN[r], e = rpN[r + 1];
  float acc = 0.f;
  for (int i = s; i < e; ++i) {
    int id = permN[i];
    acc += ned_rw[id] * embn[(size_t)nc[id] * F_FEAT + f];
  }
  Tm[(size_t)r * F_FEAT + f] = acc;
}

// ---------------- exact 3-way bf16 split: src[N][256] f32 -> 3 planes [Npad][256] bf16
__global__ void k_convert(const float* __restrict__ src,
                          unsigned short* __restrict__ p1, unsigned short* __restrict__ p2,
                          unsigned short* __restrict__ p3, int N, int Npad) {
  int idx = blockIdx.x * blockDim.x + threadIdx.x;   // one thread per 4 elems
  int total = Npad * (F_FEAT / 4);
  if (idx >= total) return;
  int row = idx >> 6;
  int c4 = (idx & 63) << 2;
  float4 v = make_float4(0.f, 0.f, 0.f, 0.f);
  if (row < N) v = *reinterpret_cast<const float4*>(src + (size_t)row * F_FEAT + c4);
  float arr[4] = {v.x, v.y, v.z, v.w};
  ushort4 o1, o2, o3;
  unsigned short* q1 = (unsigned short*)&o1;
  unsigned short* q2 = (unsigned short*)&o2;
  unsigned short* q3 = (unsigned short*)&o3;
#pragma unroll
  for (int j = 0; j < 4; ++j) {
    float a = arr[j];
    unsigned short h1 = f2bf(a);  float f1 = bf2f(h1);
    float r = a - f1;             // exact
    unsigned short h2 = f2bf(r);  float f2v = bf2f(h2);
    float r2 = r - f2v;           // exact
    unsigned short h3 = f2bf(r2); // exact (<=8 significant bits left)
    q1[j] = h1; q2[j] = h2; q3[j] = h3;
  }
  size_t off = (size_t)row * F_FEAT + c4;
  *reinterpret_cast<ushort4*>(p1 + off) = o1;
  *reinterpret_cast<ushort4*>(p2 + off) = o2;
  *reinterpret_cast<ushort4*>(p3 + off) = o3;
}

// ---------------- fused MFMA GEMM (T @ embn^T, f32-exact via 6 bf16 products) + top-5 ----
__global__ __launch_bounds__(256, 2) void k_gemm_topk(
    const unsigned short* __restrict__ A1, const unsigned short* __restrict__ A2,
    const unsigned short* __restrict__ A3,
    const unsigned short* __restrict__ B1, const unsigned short* __restrict__ B2,
    const unsigned short* __restrict__ B3,
    float* __restrict__ pv, int* __restrict__ pi, int N, int colTiles) {
  // LDS: 6 planes x [128 rows][32 k] bf16 = 6*8KB; fullscan buffer aliases the planes.
  __shared__ __align__(16) char ldsraw[49152];
  unsigned short* sA = (unsigned short*)ldsraw;            // planes 0..2: + p*4096 (ushorts)
  unsigned short* sB = (unsigned short*)(ldsraw + 24576);  // planes 0..2
  float* scan = (float*)ldsraw;                            // [32][132] fullscan buffer
  __shared__ float thr[BR];
  __shared__ float qv[QCAP];
  __shared__ unsigned qm[QCAP];
  __shared__ int qcnt;

  int tid = threadIdx.x;
  int lane = tid & 63;
  int wid = tid >> 6;
  int wr = wid >> 1, wc = wid & 1;
  int lr = lane & 15;   // row/col within 16-block
  int lg = lane >> 4;   // k-group (8 bf16 each)
  int row0 = blockIdx.x * BR;
  int per = (colTiles + NSPLIT - 1) / NSPLIT;
  int ct0 = blockIdx.y * per;
  int ct1 = min(ct0 + per, colTiles);

  float bv[5]; int bi[5];
#pragma unroll
  for (int k = 0; k < 5; ++k) { bv[k] = -FLT_MAX; bi[k] = 0x7fffffff; }
  if (tid < BR) thr[tid] = -FLT_MAX;
  if (tid == 0) qcnt = 0;
  __syncthreads();

  for (int ct = ct0; ct < ct1; ++ct) {
    int col0 = ct * BC;
    f32x4 acc[4][4];
#pragma unroll
    for (int m = 0; m < 4; ++m)
#pragma unroll
      for (int n = 0; n < 4; ++n) acc[m][n] = (f32x4){0.f, 0.f, 0.f, 0.f};

    for (int kc = 0; kc < F_FEAT; kc += 32) {
      // ---- stage 6 planes: each 128 rows x 64B; unit = 16B, 512 units/plane, 2/thread
#pragma unroll
      for (int j = 0; j < 2; ++j) {
        int u = tid + 256 * j;          // 0..511
        int r = u >> 2;                 // row in tile
        int sl = u & 3;                 // 16B slot within 64B k-slice
        size_t ga = (size_t)(row0 + r) * F_FEAT + kc + sl * 8;  // ushort units
        size_t gb = (size_t)(col0 + r) * F_FEAT + kc + sl * 8;
        float4 va1 = *reinterpret_cast<const float4*>(A1 + ga);
        float4 va2 = *reinterpret_cast<const float4*>(A2 + ga);
        float4 va3 = *reinterpret_cast<const float4*>(A3 + ga);
        float4 vb1 = *reinterpret_cast<const float4*>(B1 + gb);
        float4 vb2 = *reinterpret_cast<const float4*>(B2 + gb);
        float4 vb3 = *reinterpret_cast<const float4*>(B3 + gb);
        *reinterpret_cast<float4*>(sA + 0 * 4096 + u * 8) = va1;
        *reinterpret_cast<float4*>(sA + 1 * 4096 + u * 8) = va2;
        *reinterpret_cast<float4*>(sA + 2 * 4096 + u * 8) = va3;
        *reinterpret_cast<float4*>(sB + 0 * 4096 + u * 8) = vb1;
        *reinterpret_cast<float4*>(sB + 1 * 4096 + u * 8) = vb2;
        *reinterpret_cast<float4*>(sB + 2 * 4096 + u * 8) = vb3;
      }
      __syncthreads();

      // ---- fragments + 6-product MFMA
      bf16x8 fb[3][4];
#pragma unroll
      for (int n = 0; n < 4; ++n) {
        int crow = wc * 64 + n * 16 + lr;
#pragma unroll
        for (int p = 0; p < 3; ++p)
          fb[p][n] = *reinterpret_cast<const bf16x8*>(sB + p * 4096 + crow * 32 + lg * 8);
      }
#pragma unroll
      for (int m = 0; m < 4; ++m) {
        int arow = wr * 64 + m * 16 + lr;
        bf16x8 fa1 = *reinterpret_cast<const bf16x8*>(sA + 0 * 4096 + arow * 32 + lg * 8);
        bf16x8 fa2 = *reinterpret_cast<const bf16x8*>(sA + 1 * 4096 + arow * 32 + lg * 8);
        bf16x8 fa3 = *reinterpret_cast<const bf16x8*>(sA + 2 * 4096 + arow * 32 + lg * 8);
#pragma unroll
        for (int n = 0; n < 4; ++n) {
          acc[m][n] = __builtin_amdgcn_mfma_f32_16x16x32_bf16(fa1, fb[0][n], acc[m][n], 0, 0, 0);
          acc[m][n] = __builtin_amdgcn_mfma_f32_16x16x32_bf16(fa1, fb[1][n], acc[m][n], 0, 0, 0);
          acc[m][n] = __builtin_amdgcn_mfma_f32_16x16x32_bf16(fa2, fb[0][n], acc[m][n], 0, 0, 0);
          acc[m][n] = __builtin_amdgcn_mfma_f32_16x16x32_bf16(fa1, fb[2][n], acc[m][n], 0, 0, 0);
          acc[m][n] = __builtin_amdgcn_mfma_f32_16x16x32_bf16(fa2, fb[1][n], acc[m][n], 0, 0, 0);
          acc[m][n] = __builtin_amdgcn_mfma_f32_16x16x32_bf16(fa3, fb[0][n], acc[m][n], 0, 0, 0);
        }
      }
      __syncthreads();
    }

    // ---- top-k: threshold queue (ballot-compacted), fullscan fallback
    bool first = (ct == ct0);
    if (!first) {
#pragma unroll
      for (int m = 0; m < 4; ++m) {
#pragma unroll
        for (int rg = 0; rg < 4; ++rg) {
          int rl = wr * 64 + m * 16 + lg * 4 + rg;   // row within 128-tile
          float trr = thr[rl];
          bool rok = (row0 + rl) < N;
#pragma unroll
          for (int n = 0; n < 4; ++n) {
            float vv = acc[m][n][rg];
            int c = col0 + wc * 64 + n * 16 + lr;
            bool p = rok && (c < N) && (vv >= trr);
            unsigned long long mk = __ballot(p);
            if (mk != 0ull) {
              int leader = __ffsll((long long)mk) - 1;
              int base = 0;
              if (lane == leader) base = atomicAdd(&qcnt, __popcll(mk));
              base = __shfl(base, leader, 64);
              if (p) {
                int pos = base + __popcll(mk & ((1ull << lane) - 1ull));
                if (pos < QCAP) {
                  qv[pos] = vv;
                  qm[pos] = ((unsigned)c << 7) | (unsigned)rl;
                }
              }
            }
          }
        }
      }
    }
    __syncthreads();
    int qn = qcnt;
    bool fullscan = first || (qn > QCAP);
    if (!fullscan) {
      if (tid < BR) {
        for (int i = 0; i < qn; ++i) {
          unsigned m = qm[i];
          if ((int)(m & 127u) == tid) topk_insert5(bv, bi, qv[i], (int)(m >> 7));
        }
      }
    } else {
      // 4 passes of 32 rows via scan buffer [32][132] (aliases plane LDS)
      for (int p = 0; p < 4; ++p) {
        __syncthreads();
        if (wr == (p >> 1)) {
          int mlo = (p & 1) * 2;
#pragma unroll
          for (int mm = 0; mm < 2; ++mm) {
            int m = mlo + mm;
#pragma unroll
            for (int rg = 0; rg < 4; ++rg) {
              int rsc = m * 16 + lg * 4 + rg - (p & 1) * 32;   // 0..31
#pragma unroll
              for (int n = 0; n < 4; ++n)
                scan[rsc * 132 + wc * 64 + n * 16 + lr] = acc[m][n][rg];
            }
          }
        }
        __syncthreads();
        int rloc = tid - 32 * p;
        if (rloc >= 0 && rloc < 32) {
          for (int cdx = 0; cdx < BC; ++cdx) {
            int gc = col0 + cdx;
            if (gc < N) topk_insert5(bv, bi, scan[rloc * 132 + cdx], gc);
          }
        }
      }
      __syncthreads();
    }
    __syncthreads();
    if (tid < BR) thr[tid] = bv[4];
    if (tid == 0) qcnt = 0;
    __syncthreads();
  }

  if (tid < BR) {
    int r = row0 + tid;
    if (r < N) {
      size_t baseo = ((size_t)r * NSPLIT + blockIdx.y) * 5;
#pragma unroll
      for (int k = 0; k < 5; ++k) { pv[baseo + k] = bv[k]; pi[baseo + k] = bi[k]; }
    }
  }
}

// ---------------- merge partial top-5, build new degrees/counts ----------------
__global__ void k_merge(const float* __restrict__ pv, const int* __restrict__ pi,
                        float* __restrict__ topv, int* __restrict__ topi,
                        const float* deg_adj, float* deg_new, const int* cntA, int* cnt_new, int N) {
  int r = blockIdx.x * blockDim.x + threadIdx.x;
  if (r >= N) return;
  float v[5]; int ix[5];
#pragma unroll
  for (int k = 0; k < 5; ++k) { v[k] = -FLT_MAX; ix[k] = 0x7fffffff; }
  size_t base = (size_t)r * NSPLIT * 5;
  for (int s = 0; s < NSPLIT; ++s)
    for (int k = 0; k < 5; ++k)
      topk_insert5(v, ix, pv[base + s * 5 + k], pi[base + s * 5 + k]);
  float sumv = 0.f;
  for (int k = 0; k < 5; ++k) {
    topv[(size_t)r * 5 + k] = v[k];
    topi[(size_t)r * 5 + k] = ix[k];
    sumv += v[k];
    atomicAdd(&deg_new[ix[k]], v[k]);
    atomicAdd(&cnt_new[ix[k]], 1);
  }
  atomicAdd(&deg_new[r], deg_adj[r] + sumv);
  atomicAdd(&cnt_new[r], cntA[r] + KTOP);
}

__global__ void k_rs_new(const float* deg_new, float* rs_new, int N) {
  int i = blockIdx.x * blockDim.x + threadIdx.x;
  if (i >= N) return;
  rs_new[i] = 1.0f / (sqrtf(deg_new[i]) + 1e-10f);
}

__global__ void k_fill_new(const int* ar, const int* topi, const int* rp_new, int* fill_new,
                           int* perm_new, int E, int NK, int total) {
  int t = blockIdx.x * blockDim.x + threadIdx.x;
  if (t >= total) return;
  int r;
  if (t < E) r = ar[t];
  else if (t < E + NK) r = (t - E) / KTOP;
  else r = topi[t - E - NK];
  perm_new[rp_new[r] + atomicAdd(&fill_new[r], 1)] = t;
}

// ---------------- dense layers ----------------
__global__ void k_xw1(const float* __restrict__ x, const float* __restrict__ W1,
                      float* __restrict__ XW1, int N) {
  int c = threadIdx.x & 127;
  int half = threadIdx.x >> 7;
  int r0 = blockIdx.x * 8 + half * 4;
  int rm = N - 1;
  const float* x0 = x + (size_t)min(r0 + 0, rm) * F_FEAT;
  const float* x1 = x + (size_t)min(r0 + 1, rm) * F_FEAT;
  const float* x2 = x + (size_t)min(r0 + 2, rm) * F_FEAT;
  const float* x3 = x + (size_t)min(r0 + 3, rm) * F_FEAT;
  float a0 = 0.f, a1 = 0.f, a2 = 0.f, a3 = 0.f;
  for (int k = 0; k < F_FEAT; ++k) {
    float wv = W1[k * NHID + c];
    a0 += x0[k] * wv; a1 += x1[k] * wv; a2 += x2[k] * wv; a3 += x3[k] * wv;
  }
  if (r0 + 0 < N) XW1[(size_t)(r0 + 0) * NHID + c] = a0;
  if (r0 + 1 < N) XW1[(size_t)(r0 + 1) * NHID + c] = a1;
  if (r0 + 2 < N) XW1[(size_t)(r0 + 2) * NHID + c] = a2;
  if (r0 + 3 < N) XW1[(size_t)(r0 + 3) * NHID + c] = a3;
}

__global__ void k_spmm_h(const int* __restrict__ rp, const int* __restrict__ perm,
                         const int* __restrict__ ac, const float* __restrict__ av,
                         const int* __restrict__ topi, const float* __restrict__ topv,
                         const float* __restrict__ rs, const float* __restrict__ XW1,
                         const float* __restrict__ b1, float* __restrict__ h,
                         int N, int E, int NK) {
  int r = blockIdx.x; int f = threadIdx.x;  // 128 threads
  int s = rp[r], e = rp[r + 1];
  float acc = 0.f;
  for (int i = s; i < e; ++i) {
    int id = perm[i];
    int c; float v;
    if (id < E) { c = ac[id]; v = av[id]; }
    else if (id < E + NK) { int q = id - E; c = topi[q]; v = topv[q]; }
    else { int q = id - E - NK; c = q / KTOP; v = topv[q]; }
    acc += v * rs[c] * XW1[(size_t)c * NHID + f];
  }
  float o = rs[r] * acc + b1[f];
  h[(size_t)r * NHID + f] = fmaxf(o, 0.f);
}

__global__ void k_hw2(const float* __restrict__ h, const float* __restrict__ W2,
                      float* __restrict__ HW2, int N) {
  int tid = threadIdx.x;
  int rr = tid >> 4, c = tid & 15;
  int r = blockIdx.x * 16 + rr;
  if (r >= N) return;
  float acc = 0.f;
  for (int k = 0; k < NHID; ++k) acc += h[(size_t)r * NHID + k] * W2[k * NCLASS + c];
  HW2[(size_t)r * NCLASS + c] = acc;
}

__global__ void k_spmm_out(const int* __restrict__ rp, const int* __restrict__ perm,
                           const int* __restrict__ ac, const float* __restrict__ av,
                           const int* __restrict__ topi, const float* __restrict__ topv,
                           const float* __restrict__ rs, const float* __restrict__ HW2,
                           const float* __restrict__ b2, float* __restrict__ out,
                           int N, int E, int NK) {
  int tid = threadIdx.x;
  int rr = tid >> 4, c = tid & 15;
  int r = blockIdx.x * 16 + rr;
  if (r >= N) return;
  int s = rp[r], e = rp[r + 1];
  float acc = 0.f;
  for (int i = s; i < e; ++i) {
    int id = perm[i];
    int cc; float v;
    if (id < E) { cc = ac[id]; v = av[id]; }
    else if (id < E + NK) { int q = id - E; cc = topi[q]; v = topv[q]; }
    else { int q = id - E - NK; cc = q / KTOP; v = topv[q]; }
    acc += v * rs[cc] * HW2[(size_t)cc * NCLASS + c];
  }
  out[(size_t)r * NCLASS + c] = rs[r] * acc + b2[c];
}

// ---------------- host ----------------
extern "C" void kernel_launch(void* const* d_in, const int* in_sizes, int n_in,
                              void* d_out, int out_size, void* d_ws, size_t ws_size,
                              hipStream_t stream) {
  (void)n_in; (void)out_size; (void)ws_size;
  const float* x   = (const float*)d_in[0];
  const int*   ar  = (const int*)d_in[1];
  const int*   ac  = (const int*)d_in[2];
  const float* av  = (const float*)d_in[3];
  const int*   nr  = (const int*)d_in[4];
  const int*   nc  = (const int*)d_in[5];
  const float* nv  = (const float*)d_in[6];
  const float* Wd1 = (const float*)d_in[7];
  const float* Wd2 = (const float*)d_in[8];
  const float* W1  = (const float*)d_in[9];
  const float* b1  = (const float*)d_in[10];
  const float* W2  = (const float*)d_in[11];
  const float* b2  = (const float*)d_in[12];
  int N = in_sizes[0] / F_FEAT;
  int E = in_sizes[3];
  int NK = N * KTOP;
  int total_new = E + 2 * NK;
  int Npad = ((N + 127) / 128) * 128;

  char* w = (char*)d_ws;
  size_t off = 0;
  auto carveB = [&](size_t bytes) -> void* {
    void* p = (void*)(w + off);
    off += (bytes + 255) & ~((size_t)255);
    return p;
  };
  auto carve = [&](size_t elems) -> void* { return carveB(elems * 4); };
  size_t zstart = off;
  float* deg_adj = (float*)carve(N);
  float* deg_ned = (float*)carve(N);
  float* deg_new = (float*)carve(N);
  int* cntA = (int*)carve(N);
  int* cntN = (int*)carve(N);
  int* cnt_new = (int*)carve(N);
  int* fillA = (int*)carve(N);
  int* fillN = (int*)carve(N);
  int* fill_new = (int*)carve(N);
  size_t zbytes = off - zstart;
  float* rs_adj = (float*)carve(N);
  float* rinv_ned = (float*)carve(N);
  float* rs_new = (float*)carve(N);
  float* adj_sym = (float*)carve(E);
  float* ned_rw = (float*)carve(E);
  int* rpA = (int*)carve(N + 1);
  int* rpN = (int*)carve(N + 1);
  int* rp_new = (int*)carve(N + 1);
  int* permA = (int*)carve(E);
  int* permN = (int*)carve(E);
  int* perm_new = (int*)carve(total_new);
  float* emb  = (float*)carve((size_t)N * F_FEAT);
  float* embn = (float*)carve((size_t)N * F_FEAT);
  float* Tm   = (float*)carve((size_t)N * F_FEAT);
  float* topv = (float*)carve(NK);
  int*   topi = (int*)carve(NK);
  float* pv = (float*)carve((size_t)N * NSPLIT * 5);
  int*   pi = (int*)carve((size_t)N * NSPLIT * 5);
  float* XW1  = (float*)carve((size_t)N * NHID);
  float* hbuf = (float*)carve((size_t)N * NHID);
  float* HW2  = (float*)carve((size_t)N * NCLASS);
  size_t planeBytes = (size_t)Npad * F_FEAT * 2;
  unsigned short* TA1 = (unsigned short*)carveB(planeBytes);
  unsigned short* TA2 = (unsigned short*)carveB(planeBytes);
  unsigned short* TA3 = (unsigned short*)carveB(planeBytes);
  unsigned short* EB1 = (unsigned short*)carveB(planeBytes);
  unsigned short* EB2 = (unsigned short*)carveB(planeBytes);
  unsigned short* EB3 = (unsigned short*)carveB(planeBytes);

  hipMemsetAsync(w + zstart, 0, zbytes, stream);

  int eb = (E + 255) / 256;
  k_deg_count<<<eb, 256, 0, stream>>>(ar, av, nr, nv, deg_adj, deg_ned, cntA, cntN, E);
  k_scan_pair<<<2, 1024, 0, stream>>>(cntA, rpA, cntN, rpN, N);
  k_rs<<<(N + 255) / 256, 256, 0, stream>>>(deg_adj, deg_ned, rs_adj, rinv_ned, N);
  k_fill2<<<eb, 256, 0, stream>>>(ar, nr, rpA, rpN, fillA, fillN, permA, permN, E);
  k_edgeval<<<eb, 256, 0, stream>>>(ar, ac, av, nr, nv, rs_adj, rinv_ned, adj_sym, ned_rw, E);
  k_spmm1<<<N, F_FEAT, 0, stream>>>(rpA, permA, ac, adj_sym, x, Wd1, emb, N);
  k_spmm2_norm<<<N, F_FEAT, 0, stream>>>(rpA, permA, ac, adj_sym, emb, Wd2, embn, N);
  k_spmmT<<<N, F_FEAT, 0, stream>>>(rpN, permN, nc, ned_rw, embn, Tm, N);
  int cvb = (Npad * (F_FEAT / 4) + 255) / 256;
  k_convert<<<cvb, 256, 0, stream>>>(Tm, TA1, TA2, TA3, N, Npad);
  k_convert<<<cvb, 256, 0, stream>>>(embn, EB1, EB2, EB3, N, Npad);
  int colTiles = (N + BC - 1) / BC;
  dim3 gg((N + BR - 1) / BR, NSPLIT);
  k_gemm_topk<<<gg, 256, 0, stream>>>(TA1, TA2, TA3, EB1, EB2, EB3, pv, pi, N, colTiles);
  k_merge<<<(N + 255) / 256, 256, 0, stream>>>(pv, pi, topv, topi, deg_adj, deg_new, cntA, cnt_new, N);
  k_scan_pair<<<1, 1024, 0, stream>>>(cnt_new, rp_new, nullptr, nullptr, N);
  k_rs_new<<<(N + 255) / 256, 256, 0, stream>>>(deg_new, rs_new, N);
  k_fill_new<<<(total_new + 255) / 256, 256, 0, stream>>>(ar, topi, rp_new, fill_new, perm_new, E, NK, total_new);
  k_xw1<<<(N + 7) / 8, 256, 0, stream>>>(x, W1, XW1, N);
  k_spmm_h<<<N, NHID, 0, stream>>>(rp_new, perm_new, ac, av, topi, topv, rs_new, XW1, b1, hbuf, N, E, NK);
  k_hw2<<<(N + 15) / 16, 256, 0, stream>>>(hbuf, W2, HW2, N);
  k_spmm_out<<<(N + 15) / 16, 256, 0, stream>>>(rp_new, perm_new, ac, av, topi, topv, rs_new, HW2, b2, (float*)d_out, N, E, NK);
}

// Round 4
// 2034.004 us; speedup vs baseline: 1.2643x; 1.2643x over previous
//
#include <hip/hip_runtime.h>
#include <cfloat>
#include <cstdint>

#define F_FEAT 256
#define NHID 128
#define NCLASS 16
#define KTOP 5

#define BR 128
#define BC 128
#define NSPLIT 16
#define QCAP 448

typedef _Float16 f16x8 __attribute__((ext_vector_type(8)));
typedef __attribute__((ext_vector_type(4))) float f32x4;

// ---------------- helpers ----------------
__device__ __forceinline__ void topk_insert5(float (&v)[5], int (&ix)[5], float cv, int ci) {
  // rank order: (value desc, index asc)  -- matches jax.lax.top_k
  if (cv < v[4] || (cv == v[4] && ci > ix[4])) return;
  int pos = 0;
#pragma unroll
  for (int j = 0; j < 5; ++j) pos += ((v[j] > cv) || (v[j] == cv && ix[j] < ci)) ? 1 : 0;
  if (pos >= 5) return;
  for (int j = 4; j > pos; --j) { v[j] = v[j - 1]; ix[j] = ix[j - 1]; }
  v[pos] = cv; ix[pos] = ci;
}

__device__ __forceinline__ void gload_lds16(const void* g, void* l) {
  __builtin_amdgcn_global_load_lds((const __attribute__((address_space(1))) void*)g,
                                   (__attribute__((address_space(3))) void*)l, 16, 0, 0);
}

// ---------------- graph prep ----------------
__global__ void k_deg_count(const int* __restrict__ ar, const float* __restrict__ av,
                            const int* __restrict__ nr, const float* __restrict__ nv,
                            float* deg_adj, float* deg_ned, int* cntA, int* cntN, int E) {
  int e = blockIdx.x * blockDim.x + threadIdx.x;
  if (e >= E) return;
  int ra = ar[e]; int rn = nr[e];
  atomicAdd(&deg_adj[ra], av[e]);
  atomicAdd(&deg_ned[rn], nv[e]);
  atomicAdd(&cntA[ra], 1);
  atomicAdd(&cntN[rn], 1);
}

__global__ __launch_bounds__(1024) void k_scan_pair(const int* c0, int* o0, const int* c1, int* o1, int n) {
  const int* c = (blockIdx.x == 0) ? c0 : c1;
  int* o = (blockIdx.x == 0) ? o0 : o1;
  if (c == nullptr) return;
  __shared__ int buf[1024];
  int tid = threadIdx.x;
  int base = 0;
  int chunks = (n + 1023) >> 10;
  for (int ch = 0; ch < chunks; ++ch) {
    int i = (ch << 10) + tid;
    buf[tid] = (i < n) ? c[i] : 0;
    __syncthreads();
    for (int offd = 1; offd < 1024; offd <<= 1) {
      int t = (tid >= offd) ? buf[tid - offd] : 0;
      __syncthreads();
      buf[tid] += t;
      __syncthreads();
    }
    if (i < n) o[i + 1] = base + buf[tid];
    int tot = buf[1023];
    __syncthreads();
    base += tot;
  }
  if (tid == 0) o[0] = 0;
}

__global__ void k_rs(const float* deg_adj, const float* deg_ned, float* rs_adj, float* rinv_ned, int N) {
  int i = blockIdx.x * blockDim.x + threadIdx.x;
  if (i >= N) return;
  rs_adj[i] = 1.0f / (sqrtf(deg_adj[i]) + 1e-10f);
  rinv_ned[i] = 1.0f / (deg_ned[i] + 1e-10f);
}

__global__ void k_fill2(const int* ar, const int* nr, const int* rpA, const int* rpN,
                        int* fillA, int* fillN, int* permA, int* permN, int E) {
  int e = blockIdx.x * blockDim.x + threadIdx.x;
  if (e >= E) return;
  int ra = ar[e];
  permA[rpA[ra] + atomicAdd(&fillA[ra], 1)] = e;
  int rn = nr[e];
  permN[rpN[rn] + atomicAdd(&fillN[rn], 1)] = e;
}

__global__ void k_edgeval(const int* ar, const int* ac, const float* av,
                          const int* nr, const float* nv,
                          const float* rs_adj, const float* rinv_ned,
                          float* adj_sym, float* ned_rw, int E) {
  int e = blockIdx.x * blockDim.x + threadIdx.x;
  if (e >= E) return;
  adj_sym[e] = av[e] * rs_adj[ar[e]] * rs_adj[ac[e]];
  ned_rw[e] = nv[e] * rinv_ned[nr[e]];
}

// ---------------- SpMMs (CSR, block per row, feature per thread) ----------------
__global__ void k_spmm1(const int* __restrict__ rpA, const int* __restrict__ permA,
                        const int* __restrict__ ac, const float* __restrict__ adj_sym,
                        const float* __restrict__ x, const float* __restrict__ Wd1,
                        float* __restrict__ emb, int N) {
  int r = blockIdx.x; int f = threadIdx.x;
  int s = rpA[r], e = rpA[r + 1];
  float acc = 0.f;
  for (int i = s; i < e; ++i) {
    int id = permA[i];
    acc += adj_sym[id] * x[(size_t)ac[id] * F_FEAT + f];
  }
  emb[(size_t)r * F_FEAT + f] = tanhf(acc * Wd1[f]);
}

__global__ void k_spmm2_norm(const int* __restrict__ rpA, const int* __restrict__ permA,
                             const int* __restrict__ ac, const float* __restrict__ adj_sym,
                             const float* __restrict__ emb, const float* __restrict__ Wd2,
                             float* __restrict__ embn, int N) {
  __shared__ float red[F_FEAT];
  int r = blockIdx.x; int f = threadIdx.x;
  int s = rpA[r], e = rpA[r + 1];
  float acc = 0.f;
  for (int i = s; i < e; ++i) {
    int id = permA[i];
    acc += adj_sym[id] * emb[(size_t)ac[id] * F_FEAT + f];
  }
  float val = acc * Wd2[f];
  red[f] = val * val;
  __syncthreads();
  for (int st = F_FEAT / 2; st > 0; st >>= 1) {
    if (f < st) red[f] += red[f + st];
    __syncthreads();
  }
  float rinv = 1.0f / (sqrtf(red[0]) + 1e-12f);
  embn[(size_t)r * F_FEAT + f] = val * rinv;
}

__global__ void k_spmmT(const int* __restrict__ rpN, const int* __restrict__ permN,
                        const int* __restrict__ nc, const float* __restrict__ ned_rw,
                        const float* __restrict__ embn, float* __restrict__ Tm, int N) {
  int r = blockIdx.x; int f = threadIdx.x;
  int s = rpN[r], e = rpN[r + 1];
  float acc = 0.f;
  for (int i = s; i < e; ++i) {
    int id = permN[i];
    acc += ned_rw[id] * embn[(size_t)nc[id] * F_FEAT + f];
  }
  Tm[(size_t)r * F_FEAT + f] = acc;
}

// ---- exact 2-way fp16 split: src[N][256] f32 -> 2 planes [Npad][256] fp16 ----
__global__ void k_convert(const float* __restrict__ src,
                          unsigned short* __restrict__ p1, unsigned short* __restrict__ p2,
                          int N, int Npad) {
  int idx = blockIdx.x * blockDim.x + threadIdx.x;   // one thread per 4 elems
  int total = Npad * (F_FEAT / 4);
  if (idx >= total) return;
  int row = idx >> 6;
  int c4 = (idx & 63) << 2;
  float4 v = make_float4(0.f, 0.f, 0.f, 0.f);
  if (row < N) v = *reinterpret_cast<const float4*>(src + (size_t)row * F_FEAT + c4);
  float arr[4] = {v.x, v.y, v.z, v.w};
  ushort4 o1, o2;
  unsigned short* q1 = (unsigned short*)&o1;
  unsigned short* q2 = (unsigned short*)&o2;
#pragma unroll
  for (int j = 0; j < 4; ++j) {
    float a = arr[j];
    _Float16 h1 = (_Float16)a;
    float r = a - (float)h1;      // exact
    _Float16 h2 = (_Float16)r;    // residual of residual <= 2^-22 |a|: dropped
    q1[j] = __builtin_bit_cast(unsigned short, h1);
    q2[j] = __builtin_bit_cast(unsigned short, h2);
  }
  size_t off = (size_t)row * F_FEAT + c4;
  *reinterpret_cast<ushort4*>(p1 + off) = o1;
  *reinterpret_cast<ushort4*>(p2 + off) = o2;
}

// ---- fused MFMA GEMM (T @ embn^T, f32-faithful via 3 fp16 products) + top-5 ----
// LDS planes [128][32] fp16, source-side XOR swizzle: 16B slot s stored at s^((row>>1)&3).
__global__ __launch_bounds__(256, 4) void k_gemm_topk(
    const unsigned short* __restrict__ A1, const unsigned short* __restrict__ A2,
    const unsigned short* __restrict__ B1, const unsigned short* __restrict__ B2,
    float* __restrict__ pv, int* __restrict__ pi, int N, int colTiles) {
  __shared__ __align__(16) unsigned short planes[4 * 4096];  // 4 planes x 8KB
  float* scan = (float*)planes;                              // fullscan aliases planes
  __shared__ float thr[BR];
  __shared__ float qv[QCAP];
  __shared__ unsigned qm[QCAP];
  __shared__ int qcnt;

  int tid = threadIdx.x;
  int lane = tid & 63;
  int wid = tid >> 6;
  int wr = wid >> 1, wc = wid & 1;
  int lr = lane & 15;   // row/col within 16-block
  int lg = lane >> 4;   // k-group (8 fp16 each)
  int row0 = blockIdx.x * BR;
  int per = (colTiles + NSPLIT - 1) / NSPLIT;
  int ct0 = blockIdx.y * per;
  int ct1 = min(ct0 + per, colTiles);

  // staging: wave w owns plane w; lane covers rows lane>>2, 16B slot (lane&3)
  const unsigned short* pg = (wid == 0) ? A1 : (wid == 1) ? A2 : (wid == 2) ? B1 : B2;
  int slog = (lane & 3) ^ ((lane >> 3) & 3);   // swizzled global 16B slot
  int srow = lane >> 2;                        // row within 16-row group
  char* lbase = (char*)planes + wid * 8192;
  // read-side physical slot for fragments
  int fslot = (lg ^ ((lr >> 1) & 3)) * 8;      // ushort offset of 16B unit

  float bv[5]; int bi[5];
#pragma unroll
  for (int k = 0; k < 5; ++k) { bv[k] = -FLT_MAX; bi[k] = 0x7fffffff; }
  if (tid < BR) thr[tid] = -FLT_MAX;
  if (tid == 0) qcnt = 0;
  __syncthreads();

  for (int ct = ct0; ct < ct1; ++ct) {
    int col0 = ct * BC;
    int t0 = (wid < 2) ? row0 : col0;
    const char* gbase = (const char*)pg + (size_t)(t0 + srow) * (F_FEAT * 2) + (size_t)slog * 16;

    f32x4 acc[4][4];
#pragma unroll
    for (int m = 0; m < 4; ++m)
#pragma unroll
      for (int n = 0; n < 4; ++n) acc[m][n] = (f32x4){0.f, 0.f, 0.f, 0.f};

    for (int ks = 0; ks < 8; ++ks) {
      // ---- stage this plane's [128][32] slab via global_load_lds (8 x 1KB per wave)
      const char* g = gbase + ks * 64;
#pragma unroll
      for (int i = 0; i < 8; ++i) gload_lds16(g + i * 8192, lbase + i * 1024);
      __syncthreads();   // drains vmcnt(0): all 4 planes staged

      // ---- fragments + 3-product MFMA
      f16x8 fb[2][4];
#pragma unroll
      for (int n = 0; n < 4; ++n) {
        int crow = wc * 64 + n * 16 + lr;
        int ro = crow * 32 + fslot;
        fb[0][n] = *reinterpret_cast<const f16x8*>(planes + 2 * 4096 + ro);
        fb[1][n] = *reinterpret_cast<const f16x8*>(planes + 3 * 4096 + ro);
      }
#pragma unroll
      for (int m = 0; m < 4; ++m) {
        int arow = wr * 64 + m * 16 + lr;
        int ro = arow * 32 + fslot;
        f16x8 fa1 = *reinterpret_cast<const f16x8*>(planes + 0 * 4096 + ro);
        f16x8 fa2 = *reinterpret_cast<const f16x8*>(planes + 1 * 4096 + ro);
#pragma unroll
        for (int n = 0; n < 4; ++n) {
          acc[m][n] = __builtin_amdgcn_mfma_f32_16x16x32_f16(fa1, fb[1][n], acc[m][n], 0, 0, 0);
          acc[m][n] = __builtin_amdgcn_mfma_f32_16x16x32_f16(fa2, fb[0][n], acc[m][n], 0, 0, 0);
          acc[m][n] = __builtin_amdgcn_mfma_f32_16x16x32_f16(fa1, fb[0][n], acc[m][n], 0, 0, 0);
        }
      }
      __syncthreads();   // all reads done before next k-step overwrites planes
    }

    // ---- top-k: threshold queue (ballot-compacted), fullscan fallback
    bool first = (ct == ct0);
    if (!first) {
#pragma unroll
      for (int m = 0; m < 4; ++m) {
#pragma unroll
        for (int rg = 0; rg < 4; ++rg) {
          int rl = wr * 64 + m * 16 + lg * 4 + rg;   // row within 128-tile
          float trr = thr[rl];
          bool rok = (row0 + rl) < N;
#pragma unroll
          for (int n = 0; n < 4; ++n) {
            float vv = acc[m][n][rg];
            int c = col0 + wc * 64 + n * 16 + lr;
            bool p = rok && (c < N) && (vv >= trr);
            unsigned long long mk = __ballot(p);
            if (mk != 0ull) {
              int leader = __ffsll((long long)mk) - 1;
              int base = 0;
              if (lane == leader) base = atomicAdd(&qcnt, __popcll(mk));
              base = __shfl(base, leader, 64);
              if (p) {
                int pos = base + __popcll(mk & ((1ull << lane) - 1ull));
                if (pos < QCAP) {
                  qv[pos] = vv;
                  qm[pos] = ((unsigned)c << 7) | (unsigned)rl;
                }
              }
            }
          }
        }
      }
    }
    __syncthreads();
    int qn = qcnt;
    bool fullscan = first || (qn > QCAP);
    if (!fullscan) {
      if (tid < BR) {
        for (int i = 0; i < qn; ++i) {
          unsigned m = qm[i];
          if ((int)(m & 127u) == tid) topk_insert5(bv, bi, qv[i], (int)(m >> 7));
        }
      }
    } else {
      // 4 passes of 32 rows via scan buffer [32][132] (aliases plane LDS)
      for (int p = 0; p < 4; ++p) {
        __syncthreads();
        if (wr == (p >> 1)) {
          int mlo = (p & 1) * 2;
#pragma unroll
          for (int mm = 0; mm < 2; ++mm) {
            int m = mlo + mm;
#pragma unroll
            for (int rg = 0; rg < 4; ++rg) {
              int rsc = m * 16 + lg * 4 + rg - (p & 1) * 32;   // 0..31
#pragma unroll
              for (int n = 0; n < 4; ++n)
                scan[rsc * 132 + wc * 64 + n * 16 + lr] = acc[m][n][rg];
            }
          }
        }
        __syncthreads();
        int rloc = tid - 32 * p;
        if (rloc >= 0 && rloc < 32) {
          for (int cdx = 0; cdx < BC; ++cdx) {
            int gc = col0 + cdx;
            if (gc < N) topk_insert5(bv, bi, scan[rloc * 132 + cdx], gc);
          }
        }
      }
      __syncthreads();
    }
    __syncthreads();
    if (tid < BR) thr[tid] = bv[4];
    if (tid == 0) qcnt = 0;
    __syncthreads();
  }

  if (tid < BR) {
    int r = row0 + tid;
    if (r < N) {
      size_t baseo = ((size_t)r * NSPLIT + blockIdx.y) * 5;
#pragma unroll
      for (int k = 0; k < 5; ++k) { pv[baseo + k] = bv[k]; pi[baseo + k] = bi[k]; }
    }
  }
}

// ---------------- merge partial top-5, build new degrees/counts ----------------
__global__ void k_merge(const float* __restrict__ pv, const int* __restrict__ pi,
                        float* __restrict__ topv, int* __restrict__ topi,
                        const float* deg_adj, float* deg_new, const int* cntA, int* cnt_new, int N) {
  int r = blockIdx.x * blockDim.x + threadIdx.x;
  if (r >= N) return;
  float v[5]; int ix[5];
#pragma unroll
  for (int k = 0; k < 5; ++k) { v[k] = -FLT_MAX; ix[k] = 0x7fffffff; }
  size_t base = (size_t)r * NSPLIT * 5;
  for (int s = 0; s < NSPLIT; ++s)
    for (int k = 0; k < 5; ++k)
      topk_insert5(v, ix, pv[base + s * 5 + k], pi[base + s * 5 + k]);
  float sumv = 0.f;
  for (int k = 0; k < 5; ++k) {
    topv[(size_t)r * 5 + k] = v[k];
    topi[(size_t)r * 5 + k] = ix[k];
    sumv += v[k];
    atomicAdd(&deg_new[ix[k]], v[k]);
    atomicAdd(&cnt_new[ix[k]], 1);
  }
  atomicAdd(&deg_new[r], deg_adj[r] + sumv);
  atomicAdd(&cnt_new[r], cntA[r] + KTOP);
}

__global__ void k_rs_new(const float* deg_new, float* rs_new, int N) {
  int i = blockIdx.x * blockDim.x + threadIdx.x;
  if (i >= N) return;
  rs_new[i] = 1.0f / (sqrtf(deg_new[i]) + 1e-10f);
}

__global__ void k_fill_new(const int* ar, const int* topi, const int* rp_new, int* fill_new,
                           int* perm_new, int E, int NK, int total) {
  int t = blockIdx.x * blockDim.x + threadIdx.x;
  if (t >= total) return;
  int r;
  if (t < E) r = ar[t];
  else if (t < E + NK) r = (t - E) / KTOP;
  else r = topi[t - E - NK];
  perm_new[rp_new[r] + atomicAdd(&fill_new[r], 1)] = t;
}

// ---------------- dense layers ----------------
__global__ void k_xw1(const float* __restrict__ x, const float* __restrict__ W1,
                      float* __restrict__ XW1, int N) {
  int c = threadIdx.x & 127;
  int half = threadIdx.x >> 7;
  int r0 = blockIdx.x * 8 + half * 4;
  int rm = N - 1;
  const float* x0 = x + (size_t)min(r0 + 0, rm) * F_FEAT;
  const float* x1 = x + (size_t)min(r0 + 1, rm) * F_FEAT;
  const float* x2 = x + (size_t)min(r0 + 2, rm) * F_FEAT;
  const float* x3 = x + (size_t)min(r0 + 3, rm) * F_FEAT;
  float a0 = 0.f, a1 = 0.f, a2 = 0.f, a3 = 0.f;
  for (int k = 0; k < F_FEAT; ++k) {
    float wv = W1[k * NHID + c];
    a0 += x0[k] * wv; a1 += x1[k] * wv; a2 += x2[k] * wv; a3 += x3[k] * wv;
  }
  if (r0 + 0 < N) XW1[(size_t)(r0 + 0) * NHID + c] = a0;
  if (r0 + 1 < N) XW1[(size_t)(r0 + 1) * NHID + c] = a1;
  if (r0 + 2 < N) XW1[(size_t)(r0 + 2) * NHID + c] = a2;
  if (r0 + 3 < N) XW1[(size_t)(r0 + 3) * NHID + c] = a3;
}

__global__ void k_spmm_h(const int* __restrict__ rp, const int* __restrict__ perm,
                         const int* __restrict__ ac, const float* __restrict__ av,
                         const int* __restrict__ topi, const float* __restrict__ topv,
                         const float* __restrict__ rs, const float* __restrict__ XW1,
                         const float* __restrict__ b1, float* __restrict__ h,
                         int N, int E, int NK) {
  int r = blockIdx.x; int f = threadIdx.x;  // 128 threads
  int s = rp[r], e = rp[r + 1];
  float acc = 0.f;
  for (int i = s; i < e; ++i) {
    int id = perm[i];
    int c; float v;
    if (id < E) { c = ac[id]; v = av[id]; }
    else if (id < E + NK) { int q = id - E; c = topi[q]; v = topv[q]; }
    else { int q = id - E - NK; c = q / KTOP; v = topv[q]; }
    acc += v * rs[c] * XW1[(size_t)c * NHID + f];
  }
  float o = rs[r] * acc + b1[f];
  h[(size_t)r * NHID + f] = fmaxf(o, 0.f);
}

__global__ void k_hw2(const float* __restrict__ h, const float* __restrict__ W2,
                      float* __restrict__ HW2, int N) {
  int tid = threadIdx.x;
  int rr = tid >> 4, c = tid & 15;
  int r = blockIdx.x * 16 + rr;
  if (r >= N) return;
  float acc = 0.f;
  for (int k = 0; k < NHID; ++k) acc += h[(size_t)r * NHID + k] * W2[k * NCLASS + c];
  HW2[(size_t)r * NCLASS + c] = acc;
}

__global__ void k_spmm_out(const int* __restrict__ rp, const int* __restrict__ perm,
                           const int* __restrict__ ac, const float* __restrict__ av,
                           const int* __restrict__ topi, const float* __restrict__ topv,
                           const float* __restrict__ rs, const float* __restrict__ HW2,
                           const float* __restrict__ b2, float* __restrict__ out,
                           int N, int E, int NK) {
  int tid = threadIdx.x;
  int rr = tid >> 4, c = tid & 15;
  int r = blockIdx.x * 16 + rr;
  if (r >= N) return;
  int s = rp[r], e = rp[r + 1];
  float acc = 0.f;
  for (int i = s; i < e; ++i) {
    int id = perm[i];
    int cc; float v;
    if (id < E) { cc = ac[id]; v = av[id]; }
    else if (id < E + NK) { int q = id - E; cc = topi[q]; v = topv[q]; }
    else { int q = id - E - NK; cc = q / KTOP; v = topv[q]; }
    acc += v * rs[cc] * HW2[(size_t)cc * NCLASS + c];
  }
  out[(size_t)r * NCLASS + c] = rs[r] * acc + b2[c];
}

// ---------------- host ----------------
extern "C" void kernel_launch(void* const* d_in, const int* in_sizes, int n_in,
                              void* d_out, int out_size, void* d_ws, size_t ws_size,
                              hipStream_t stream) {
  (void)n_in; (void)out_size; (void)ws_size;
  const float* x   = (const float*)d_in[0];
  const int*   ar  = (const int*)d_in[1];
  const int*   ac  = (const int*)d_in[2];
  const float* av  = (const float*)d_in[3];
  const int*   nr  = (const int*)d_in[4];
  const int*   nc  = (const int*)d_in[5];
  const float* nv  = (const float*)d_in[6];
  const float* Wd1 = (const float*)d_in[7];
  const float* Wd2 = (const float*)d_in[8];
  const float* W1  = (const float*)d_in[9];
  const float* b1  = (const float*)d_in[10];
  const float* W2  = (const float*)d_in[11];
  const float* b2  = (const float*)d_in[12];
  int N = in_sizes[0] / F_FEAT;
  int E = in_sizes[3];
  int NK = N * KTOP;
  int total_new = E + 2 * NK;
  int Npad = ((N + 127) / 128) * 128;

  char* w = (char*)d_ws;
  size_t off = 0;
  auto carveB = [&](size_t bytes) -> void* {
    void* p = (void*)(w + off);
    off += (bytes + 255) & ~((size_t)255);
    return p;
  };
  auto carve = [&](size_t elems) -> void* { return carveB(elems * 4); };
  size_t zstart = off;
  float* deg_adj = (float*)carve(N);
  float* deg_ned = (float*)carve(N);
  float* deg_new = (float*)carve(N);
  int* cntA = (int*)carve(N);
  int* cntN = (int*)carve(N);
  int* cnt_new = (int*)carve(N);
  int* fillA = (int*)carve(N);
  int* fillN = (int*)carve(N);
  int* fill_new = (int*)carve(N);
  size_t zbytes = off - zstart;
  float* rs_adj = (float*)carve(N);
  float* rinv_ned = (float*)carve(N);
  float* rs_new = (float*)carve(N);
  float* adj_sym = (float*)carve(E);
  float* ned_rw = (float*)carve(E);
  int* rpA = (int*)carve(N + 1);
  int* rpN = (int*)carve(N + 1);
  int* rp_new = (int*)carve(N + 1);
  int* permA = (int*)carve(E);
  int* permN = (int*)carve(E);
  int* perm_new = (int*)carve(total_new);
  float* emb  = (float*)carve((size_t)N * F_FEAT);
  float* embn = (float*)carve((size_t)N * F_FEAT);
  float* Tm   = (float*)carve((size_t)N * F_FEAT);
  float* topv = (float*)carve(NK);
  int*   topi = (int*)carve(NK);
  float* pv = (float*)carve((size_t)N * NSPLIT * 5);
  int*   pi = (int*)carve((size_t)N * NSPLIT * 5);
  float* XW1  = (float*)carve((size_t)N * NHID);
  float* hbuf = (float*)carve((size_t)N * NHID);
  float* HW2  = (float*)carve((size_t)N * NCLASS);
  size_t planeBytes = (size_t)Npad * F_FEAT * 2;
  unsigned short* TA1 = (unsigned short*)carveB(planeBytes);
  unsigned short* TA2 = (unsigned short*)carveB(planeBytes);
  unsigned short* EB1 = (unsigned short*)carveB(planeBytes);
  unsigned short* EB2 = (unsigned short*)carveB(planeBytes);

  hipMemsetAsync(w + zstart, 0, zbytes, stream);

  int eb = (E + 255) / 256;
  k_deg_count<<<eb, 256, 0, stream>>>(ar, av, nr, nv, deg_adj, deg_ned, cntA, cntN, E);
  k_scan_pair<<<2, 1024, 0, stream>>>(cntA, rpA, cntN, rpN, N);
  k_rs<<<(N + 255) / 256, 256, 0, stream>>>(deg_adj, deg_ned, rs_adj, rinv_ned, N);
  k_fill2<<<eb, 256, 0, stream>>>(ar, nr, rpA, rpN, fillA, fillN, permA, permN, E);
  k_edgeval<<<eb, 256, 0, stream>>>(ar, ac, av, nr, nv, rs_adj, rinv_ned, adj_sym, ned_rw, E);
  k_spmm1<<<N, F_FEAT, 0, stream>>>(rpA, permA, ac, adj_sym, x, Wd1, emb, N);
  k_spmm2_norm<<<N, F_FEAT, 0, stream>>>(rpA, permA, ac, adj_sym, emb, Wd2, embn, N);
  k_spmmT<<<N, F_FEAT, 0, stream>>>(rpN, permN, nc, ned_rw, embn, Tm, N);
  int cvb = (Npad * (F_FEAT / 4) + 255) / 256;
  k_convert<<<cvb, 256, 0, stream>>>(Tm, TA1, TA2, N, Npad);
  k_convert<<<cvb, 256, 0, stream>>>(embn, EB1, EB2, N, Npad);
  int colTiles = (N + BC - 1) / BC;
  dim3 gg((N + BR - 1) / BR, NSPLIT);
  k_gemm_topk<<<gg, 256, 0, stream>>>(TA1, TA2, EB1, EB2, pv, pi, N, colTiles);
  k_merge<<<(N + 255) / 256, 256, 0, stream>>>(pv, pi, topv, topi, deg_adj, deg_new, cntA, cnt_new, N);
  k_scan_pair<<<1, 1024, 0, stream>>>(cnt_new, rp_new, nullptr, nullptr, N);
  k_rs_new<<<(N + 255) / 256, 256, 0, stream>>>(deg_new, rs_new, N);
  k_fill_new<<<(total_new + 255) / 256, 256, 0, stream>>>(ar, topi, rp_new, fill_new, perm_new, E, NK, total_new);
  k_xw1<<<(N + 7) / 8, 256, 0, stream>>>(x, W1, XW1, N);
  k_spmm_h<<<N, NHID, 0, stream>>>(rp_new, perm_new, ac, av, topi, topv, rs_new, XW1, b1, hbuf, N, E, NK);
  k_hw2<<<(N + 15) / 16, 256, 0, stream>>>(hbuf, W2, HW2, N);
  k_spmm_out<<<(N + 15) / 16, 256, 0, stream>>>(rp_new, perm_new, ac, av, topi, topv, rs_new, HW2, b2, (float*)d_out, N, E, NK);
}